// Round 16
// baseline (170.108 us; speedup 1.0000x reference)
//
#include <hip/hip_runtime.h>

#define N_NODES 50000
#define N_EDGES 800000
#define DIM 128
#define N_GRAPHS 64
#define NTILES 3125   // N_NODES / 16
#define NB 196        // buckets of 256 nodes: ceil(50000/256)
#define GPART 256     // partition blocks for bucketing
#define EPB 3125      // N_EDGES / GPART (exact)
#define XBF_BLKS 6250 // float4 blocks for x->bf16

typedef __attribute__((ext_vector_type(8))) short short8;
typedef __attribute__((ext_vector_type(4))) float f32x4;

__device__ __forceinline__ float bf2f(unsigned short h) {
  unsigned int u = ((unsigned int)h) << 16;
  return __builtin_bit_cast(float, u);
}
__device__ __forceinline__ unsigned short f2bf(float f) {
  unsigned int u = __builtin_bit_cast(unsigned int, f);
  u += 0x7FFFu + ((u >> 16) & 1u);
  return (unsigned short)(u >> 16);
}

// ---------------- front kernel: hist + xbf + wprep/zero/gcnt ----------------
__global__ __launch_bounds__(256) void k_front(
    const int* __restrict__ ei, int* __restrict__ cnt,
    const float* __restrict__ x, unsigned short* __restrict__ xbf,
    const float* __restrict__ w0, const float* __restrict__ w1,
    const float* __restrict__ w2, const float* __restrict__ w3,
    const float* __restrict__ w4, const float* __restrict__ w5,
    unsigned short* __restrict__ wfrag, float* __restrict__ out,
    const int* __restrict__ batch, float* __restrict__ inv_gcnt) {
  int blk = blockIdx.x, tid = threadIdx.x;
  if (blk < GPART) {
    __shared__ int h[NB];
    if (tid < NB) h[tid] = 0;
    __syncthreads();
    int e0 = blk * EPB;
    for (int i = tid; i < EPB; i += 256) {
      int dst = ei[N_EDGES + e0 + i];
      atomicAdd(&h[dst >> 8], 1);
    }
    __syncthreads();
    if (tid < NB) cnt[blk * NB + tid] = h[tid];
  } else if (blk < GPART + XBF_BLKS) {
    int i = (blk - GPART) * 256 + tid;  // one float4 per thread
    if (i * 4 >= N_NODES * DIM) return;
    float4 v = ((const float4*)x)[i];
    unsigned int lo = (unsigned int)f2bf(v.x) | ((unsigned int)f2bf(v.y) << 16);
    unsigned int hi = (unsigned int)f2bf(v.z) | ((unsigned int)f2bf(v.w) << 16);
    uint2 o; o.x = lo; o.y = hi;
    ((uint2*)xbf)[i] = o;
  } else {
    int b = blk - GPART - XBF_BLKS;  // 0..80
    if (b < 48) {
      int idx = b * 256 + tid;  // 6 * 2048
      int mat = idx >> 11;
      int rem = idx & 2047;
      int lane = rem & 63;
      int kk = (rem >> 6) & 3;
      int t = rem >> 8;
      const float* w = (mat == 0) ? w0 : (mat == 1) ? w1 : (mat == 2) ? w2
                     : (mat == 3) ? w3 : (mat == 4) ? w4 : w5;
      int row = t * 16 + (lane & 15);          // output column c
      int k0 = kk * 32 + (lane >> 4) * 8;
      unsigned int v[8];
      #pragma unroll
      for (int j = 0; j < 8; ++j) v[j] = f2bf(w[(k0 + j) * DIM + row]);
      uint4 o;
      o.x = v[0] | (v[1] << 16);
      o.y = v[2] | (v[3] << 16);
      o.z = v[4] | (v[5] << 16);
      o.w = v[6] | (v[7] << 16);
      ((uint4*)wfrag)[idx] = o;
    } else if (b < 80) {
      int i = (b - 48) * 256 + tid;
      if (i < N_GRAPHS * DIM) out[i] = 0.f;
    } else {
      int g = tid;  // 0..63
      if (g >= N_GRAPHS) return;
      int lo = 0, hi = N_NODES;
      while (lo < hi) { int m = (lo + hi) >> 1; if (batch[m] < g) lo = m + 1; else hi = m; }
      int s = lo;
      lo = 0; hi = N_NODES;
      int g1 = g + 1;
      while (lo < hi) { int m = (lo + hi) >> 1; if (batch[m] < g1) lo = m + 1; else hi = m; }
      int c = lo - s;
      inv_gcnt[g] = 1.0f / (float)(c > 1 ? c : 1);
    }
  }
}

// ---------------- CSR build (bucketed counting sort, no global atomics) ----

__global__ void k_escan(int* __restrict__ cnt, int* __restrict__ bb) {
  __shared__ int s[256];
  int t = threadIdx.x;
  int tot = 0;
  if (t < NB)
    for (int g = 0; g < GPART; ++g) tot += cnt[g * NB + t];
  s[t] = (t < NB) ? tot : 0;
  __syncthreads();
  for (int off = 1; off < 256; off <<= 1) {
    int v = (t >= off) ? s[t - off] : 0;
    __syncthreads();
    s[t] += v;
    __syncthreads();
  }
  if (t < NB) {
    int excl = s[t] - tot;
    bb[t] = excl;
    if (t == NB - 1) bb[NB] = s[t];  // == N_EDGES
    int run = excl;
    for (int g = 0; g < GPART; ++g) {
      int c = cnt[g * NB + t];
      cnt[g * NB + t] = run;
      run += c;
    }
  }
}

__global__ __launch_bounds__(256) void k_bucket(const int* __restrict__ ei,
                                                const int* __restrict__ cnt,
                                                unsigned int* __restrict__ bucketed) {
  __shared__ int lofs[NB];
  int t = threadIdx.x, g = blockIdx.x;
  if (t < NB) lofs[t] = cnt[g * NB + t];
  __syncthreads();
  int e0 = g * EPB;
  for (int i = t; i < EPB; i += 256) {
    int src = ei[e0 + i];
    int dst = ei[N_EDGES + e0 + i];
    int p = atomicAdd(&lofs[dst >> 8], 1);
    bucketed[p] = (unsigned int)src | ((unsigned int)(dst & 255) << 16);
  }
}

__global__ __launch_bounds__(256) void k_finalize(const unsigned int* __restrict__ bucketed,
                                                  const int* __restrict__ bb,
                                                  int* __restrict__ rowptr,
                                                  int* __restrict__ col) {
  __shared__ int h[256], s[256], c[256];
  int t = threadIdx.x, b = blockIdx.x;
  int s0 = bb[b], s1 = bb[b + 1];
  int n = s1 - s0;
  h[t] = 0;
  __syncthreads();
  for (int i = t; i < n; i += 256) atomicAdd(&h[bucketed[s0 + i] >> 16], 1);
  __syncthreads();
  s[t] = h[t];
  __syncthreads();
  for (int off = 1; off < 256; off <<= 1) {
    int v = (t >= off) ? s[t - off] : 0;
    __syncthreads();
    s[t] += v;
    __syncthreads();
  }
  int excl = s[t] - h[t];
  int node = b * 256 + t;
  if (node < N_NODES) rowptr[node] = s0 + excl;
  if (b == NB - 1 && t == 255) rowptr[N_NODES] = N_EDGES;
  c[t] = s0 + excl;
  __syncthreads();
  for (int i = t; i < n; i += 256) {
    unsigned int v = bucketed[s0 + i];
    int p = atomicAdd(&c[v >> 16], 1);
    col[p] = (int)(v & 0xffffu);
  }
}

// ---------------- per-layer kernels ----------------

#define ACC8(V)                                   \
  a0 += bf2f((unsigned short)((V).x & 0xffff));   \
  a1 += bf2f((unsigned short)((V).x >> 16));      \
  a2 += bf2f((unsigned short)((V).y & 0xffff));   \
  a3 += bf2f((unsigned short)((V).y >> 16));      \
  a4 += bf2f((unsigned short)((V).z & 0xffff));   \
  a5 += bf2f((unsigned short)((V).z >> 16));      \
  a6 += bf2f((unsigned short)((V).w & 0xffff));   \
  a7 += bf2f((unsigned short)((V).w >> 16));

__global__ __launch_bounds__(256) void k_agg(const unsigned short* __restrict__ xin,
                                             const int* __restrict__ rowptr,
                                             const int* __restrict__ col,
                                             unsigned short* __restrict__ meanbf) {
  int wid = (blockIdx.x * blockDim.x + threadIdx.x) >> 6;
  int lane = threadIdx.x & 63;
  if (wid >= N_NODES) return;
  int start = rowptr[wid], end = rowptr[wid + 1];
  int g = lane >> 4;    // neighbor slot 0..3
  int li = lane & 15;   // 16B chunk index within row

  float a0 = 0.f, a1 = 0.f, a2 = 0.f, a3 = 0.f;
  float a4 = 0.f, a5 = 0.f, a6 = 0.f, a7 = 0.f;
  for (int j0 = start; j0 < end; j0 += 64) {
    int m = end - j0;
    if (m > 64) m = 64;
    int idx = (lane < m) ? col[j0 + lane] : 0;
    int jj = g;
    if (jj < m) {
      int nb = __shfl(idx, jj);
      uint4 v = *(const uint4*)(xin + (size_t)nb * DIM + li * 8);
      jj += 4;
      if (jj < m) {
        int nb2 = __shfl(idx, jj);
        uint4 w = *(const uint4*)(xin + (size_t)nb2 * DIM + li * 8);
        for (jj += 4; jj < m; jj += 4) {
          int nb3 = __shfl(idx, jj);
          uint4 u = *(const uint4*)(xin + (size_t)nb3 * DIM + li * 8);
          ACC8(v);
          v = w;
          w = u;
        }
        ACC8(v);
        v = w;
      }
      ACC8(v);
    }
  }
  // reduce the 4 groups (lanes sharing li)
  a0 += __shfl_xor(a0, 16); a0 += __shfl_xor(a0, 32);
  a1 += __shfl_xor(a1, 16); a1 += __shfl_xor(a1, 32);
  a2 += __shfl_xor(a2, 16); a2 += __shfl_xor(a2, 32);
  a3 += __shfl_xor(a3, 16); a3 += __shfl_xor(a3, 32);
  a4 += __shfl_xor(a4, 16); a4 += __shfl_xor(a4, 32);
  a5 += __shfl_xor(a5, 16); a5 += __shfl_xor(a5, 32);
  a6 += __shfl_xor(a6, 16); a6 += __shfl_xor(a6, 32);
  a7 += __shfl_xor(a7, 16); a7 += __shfl_xor(a7, 32);

  if (g == 0) {
    int d = end - start;
    float sc = 1.0f / (float)(d > 1 ? d : 1);
    uint4 o;
    o.x = (unsigned int)f2bf(a0 * sc) | ((unsigned int)f2bf(a1 * sc) << 16);
    o.y = (unsigned int)f2bf(a2 * sc) | ((unsigned int)f2bf(a3 * sc) << 16);
    o.z = (unsigned int)f2bf(a4 * sc) | ((unsigned int)f2bf(a5 * sc) << 16);
    o.w = (unsigned int)f2bf(a6 * sc) | ((unsigned int)f2bf(a7 * sc) << 16);
    *(uint4*)(meanbf + (size_t)wid * DIM + li * 8) = o;
  }
}

// fused: h = [relu](mean @ Wl + xin @ Wr + b), row l2-normalize.
// 8 waves/block (512 thr). If pool_out != nullptr (layer 3): skip h store,
// accumulate graph-mean-pool directly (f32, pre-scaled by 1/count).
__global__ __launch_bounds__(512) void k_gemm(const unsigned short* __restrict__ meanbf,
                                              const unsigned short* __restrict__ xin,
                                              const unsigned short* __restrict__ wfragL,
                                              const unsigned short* __restrict__ wfragR,
                                              const float* __restrict__ bias,
                                              unsigned short* __restrict__ outbf,
                                              int relu,
                                              const int* __restrict__ batch,
                                              const float* __restrict__ inv_gcnt,
                                              float* __restrict__ pool_out) {
  __shared__ __align__(16) unsigned short wl[8 * 4 * 64 * 8];  // 32 KB
  __shared__ __align__(16) unsigned short wr[8 * 4 * 64 * 8];  // 32 KB
  const int tid = threadIdx.x;
  int wave = tid >> 6;
  int lane = tid & 63;
  int tb = blockIdx.x * 8 + wave;
  int lg = lane >> 4;   // 0..3
  int li = lane & 15;   // 0..15

  // A fragments first (global loads issue early, overlap LDS staging below)
  short8 am[4], ax[4];
  {
    int tbc = (tb < NTILES) ? tb : (NTILES - 1);
    const unsigned short* mrow = meanbf + ((size_t)(tbc * 16 + li)) * DIM + lg * 8;
    const unsigned short* xrow = xin + ((size_t)(tbc * 16 + li)) * DIM + lg * 8;
    #pragma unroll
    for (int kk = 0; kk < 4; ++kk) {
      am[kk] = *(const short8*)(mrow + kk * 32);
      ax[kk] = *(const short8*)(xrow + kk * 32);
    }
  }

  {
    const uint4* gl = (const uint4*)wfragL;
    const uint4* gr = (const uint4*)wfragR;
    uint4* sl = (uint4*)wl;
    uint4* sr = (uint4*)wr;
    #pragma unroll
    for (int i = 0; i < 4; ++i) {  // 2048 uint4 per array / 512 threads
      sl[tid + 512 * i] = gl[tid + 512 * i];
      sr[tid + 512 * i] = gr[tid + 512 * i];
    }
  }
  __syncthreads();
  if (tb >= NTILES) return;

  f32x4 acc[8];
  #pragma unroll
  for (int t = 0; t < 8; ++t) {
    f32x4 c = {0.f, 0.f, 0.f, 0.f};
    #pragma unroll
    for (int kk = 0; kk < 4; ++kk) {
      short8 bl = *(const short8*)(wl + (((t * 4 + kk) * 64 + lane) * 8));
      c = __builtin_amdgcn_mfma_f32_16x16x32_bf16(am[kk], bl, c, 0, 0, 0);
      short8 br = *(const short8*)(wr + (((t * 4 + kk) * 64 + lane) * 8));
      c = __builtin_amdgcn_mfma_f32_16x16x32_bf16(ax[kk], br, c, 0, 0, 0);
    }
    float bv = bias[t * 16 + li];
    #pragma unroll
    for (int r = 0; r < 4; ++r) {
      float v = c[r] + bv;
      if (relu) v = fmaxf(v, 0.f);
      c[r] = v;
    }
    acc[t] = c;
  }

  // l2 norm per output row: row = tb*16 + lg*4 + r; cols spread over t and li.
  float scale[4];
  #pragma unroll
  for (int r = 0; r < 4; ++r) {
    float s = 0.f;
    #pragma unroll
    for (int t = 0; t < 8; ++t) s += acc[t][r] * acc[t][r];
    s += __shfl_xor(s, 1);
    s += __shfl_xor(s, 2);
    s += __shfl_xor(s, 4);
    s += __shfl_xor(s, 8);
    float n = sqrtf(s);
    scale[r] = 1.0f / fmaxf(n, 1e-12f);
  }

  if (pool_out) {
    // fused global-mean-pool; batch sorted -> few graphs per tile.
    int rowbase = tb * 16 + lg * 4;
    int bg[4];
    #pragma unroll
    for (int r = 0; r < 4; ++r) bg[r] = batch[rowbase + r];
    int g_cur = batch[tb * 16];  // wave-uniform
    while (true) {
      float p[8];
      #pragma unroll
      for (int t = 0; t < 8; ++t) {
        float s = 0.f;
        #pragma unroll
        for (int r = 0; r < 4; ++r)
          if (bg[r] == g_cur) s += acc[t][r] * scale[r];
        p[t] = s;
      }
      #pragma unroll
      for (int t = 0; t < 8; ++t) {
        p[t] += __shfl_xor(p[t], 16);
        p[t] += __shfl_xor(p[t], 32);
      }
      if (lg == 0) {
        float inv = inv_gcnt[g_cur];
        #pragma unroll
        for (int t = 0; t < 8; ++t)
          atomicAdd(&pool_out[g_cur * DIM + t * 16 + li], p[t] * inv);
      }
      // next graph id within this 16-row tile (bg uniform across li lanes)
      int nxt = 0x7fffffff;
      #pragma unroll
      for (int r = 0; r < 4; ++r)
        if (bg[r] > g_cur && bg[r] < nxt) nxt = bg[r];
      nxt = min(nxt, __shfl_xor(nxt, 16));
      nxt = min(nxt, __shfl_xor(nxt, 32));
      if (nxt == 0x7fffffff) break;
      g_cur = nxt;
    }
  } else {
    #pragma unroll
    for (int t = 0; t < 8; ++t) {
      #pragma unroll
      for (int r = 0; r < 4; ++r) {
        outbf[((size_t)(tb * 16 + lg * 4 + r)) * DIM + t * 16 + li] =
            f2bf(acc[t][r] * scale[r]);
      }
    }
  }
}

// ---------------- launch ----------------

extern "C" void kernel_launch(void* const* d_in, const int* in_sizes, int n_in,
                              void* d_out, int out_size, void* d_ws, size_t ws_size,
                              hipStream_t stream) {
  const float* x   = (const float*)d_in[0];
  const int* ei    = (const int*)d_in[1];
  const int* batch = (const int*)d_in[2];
  const float* Wl1 = (const float*)d_in[3];
  const float* Wr1 = (const float*)d_in[4];
  const float* b1  = (const float*)d_in[5];
  const float* Wl2 = (const float*)d_in[6];
  const float* Wr2 = (const float*)d_in[7];
  const float* b2  = (const float*)d_in[8];
  const float* Wl3 = (const float*)d_in[9];
  const float* Wr3 = (const float*)d_in[10];
  const float* b3  = (const float*)d_in[11];
  float* out = (float*)d_out;

  char* ws = (char*)d_ws;
  size_t off = 0;
  auto alloc = [&](size_t bytes) {
    void* p = ws + off;
    off += (bytes + 255) & ~(size_t)255;
    return p;
  };
  unsigned short* xbf   = (unsigned short*)alloc((size_t)N_NODES * DIM * 2);
  unsigned short* hB    = (unsigned short*)alloc((size_t)N_NODES * DIM * 2);
  unsigned short* hC    = (unsigned short*)alloc((size_t)N_NODES * DIM * 2);
  unsigned short* mean  = (unsigned short*)alloc((size_t)N_NODES * DIM * 2);
  unsigned short* wfrag = (unsigned short*)alloc((size_t)6 * 2048 * 16);
  int* rowptr = (int*)alloc((size_t)(N_NODES + 1) * 4);
  int* col    = (int*)alloc((size_t)N_EDGES * 4);
  int* cnt    = (int*)alloc((size_t)GPART * NB * 4);
  int* bb     = (int*)alloc((size_t)(NB + 1) * 4);
  unsigned int* bucketed = (unsigned int*)alloc((size_t)N_EDGES * 4);
  float* inv_gcnt = (float*)alloc((size_t)N_GRAPHS * 4);

  // front: hist + xbf + (wfrag, zero out, inv_gcnt)
  k_front<<<GPART + XBF_BLKS + 81, 256, 0, stream>>>(
      ei, cnt, x, xbf, Wl1, Wr1, Wl2, Wr2, Wl3, Wr3, wfrag, out, batch, inv_gcnt);

  // CSR build
  k_escan<<<1, 256, 0, stream>>>(cnt, bb);
  k_bucket<<<GPART, 256, 0, stream>>>(ei, cnt, bucketed);
  k_finalize<<<NB, 256, 0, stream>>>(bucketed, bb, rowptr, col);

  // layer 1
  k_agg<<<12500, 256, 0, stream>>>(xbf, rowptr, col, mean);
  k_gemm<<<391, 512, 0, stream>>>(mean, xbf, wfrag + 0 * 16384, wfrag + 1 * 16384,
                                  b1, hB, 1, batch, inv_gcnt, nullptr);
  // layer 2
  k_agg<<<12500, 256, 0, stream>>>(hB, rowptr, col, mean);
  k_gemm<<<391, 512, 0, stream>>>(mean, hB, wfrag + 2 * 16384, wfrag + 3 * 16384,
                                  b2, hC, 1, batch, inv_gcnt, nullptr);
  // layer 3 (fused mean-pool with pre-scaled 1/count, no h store, no k_div)
  k_agg<<<12500, 256, 0, stream>>>(hC, rowptr, col, mean);
  k_gemm<<<391, 512, 0, stream>>>(mean, hC, wfrag + 4 * 16384, wfrag + 5 * 16384,
                                  b3, nullptr, 0, batch, inv_gcnt, out);
}

// Round 17
// 167.188 us; speedup vs baseline: 1.0175x; 1.0175x over previous
//
#include <hip/hip_runtime.h>

#define N_NODES 50000
#define N_EDGES 800000
#define DIM 128
#define N_GRAPHS 64
#define NTILES 3125   // N_NODES / 16
#define NB 196        // buckets of 256 nodes: ceil(50000/256)
#define GPART 256     // partition blocks for bucketing
#define EPB 3125      // N_EDGES / GPART (exact)
#define XBF_BLKS 6250 // float4 blocks for x->bf16

typedef __attribute__((ext_vector_type(8))) short short8;
typedef __attribute__((ext_vector_type(4))) float f32x4;

__device__ __forceinline__ float bf2f(unsigned short h) {
  unsigned int u = ((unsigned int)h) << 16;
  return __builtin_bit_cast(float, u);
}
__device__ __forceinline__ unsigned short f2bf(float f) {
  unsigned int u = __builtin_bit_cast(unsigned int, f);
  u += 0x7FFFu + ((u >> 16) & 1u);
  return (unsigned short)(u >> 16);
}

// ---------------- front kernel: hist + xbf + wprep/zero/gcnt ----------------
__global__ __launch_bounds__(256) void k_front(
    const int* __restrict__ ei, int* __restrict__ cnt,
    const float* __restrict__ x, unsigned short* __restrict__ xbf,
    const float* __restrict__ w0, const float* __restrict__ w1,
    const float* __restrict__ w2, const float* __restrict__ w3,
    const float* __restrict__ w4, const float* __restrict__ w5,
    unsigned short* __restrict__ wfrag, float* __restrict__ out,
    const int* __restrict__ batch, float* __restrict__ inv_gcnt) {
  int blk = blockIdx.x, tid = threadIdx.x;
  if (blk < GPART) {
    __shared__ int h[NB];
    if (tid < NB) h[tid] = 0;
    __syncthreads();
    int e0 = blk * EPB;
    for (int i = tid; i < EPB; i += 256) {
      int dst = ei[N_EDGES + e0 + i];
      atomicAdd(&h[dst >> 8], 1);
    }
    __syncthreads();
    if (tid < NB) cnt[blk * NB + tid] = h[tid];
  } else if (blk < GPART + XBF_BLKS) {
    int i = (blk - GPART) * 256 + tid;  // one float4 per thread
    if (i * 4 >= N_NODES * DIM) return;
    float4 v = ((const float4*)x)[i];
    unsigned int lo = (unsigned int)f2bf(v.x) | ((unsigned int)f2bf(v.y) << 16);
    unsigned int hi = (unsigned int)f2bf(v.z) | ((unsigned int)f2bf(v.w) << 16);
    uint2 o; o.x = lo; o.y = hi;
    ((uint2*)xbf)[i] = o;
  } else {
    int b = blk - GPART - XBF_BLKS;  // 0..80
    if (b < 48) {
      int idx = b * 256 + tid;  // 6 * 2048
      int mat = idx >> 11;
      int rem = idx & 2047;
      int lane = rem & 63;
      int kk = (rem >> 6) & 3;
      int t = rem >> 8;
      const float* w = (mat == 0) ? w0 : (mat == 1) ? w1 : (mat == 2) ? w2
                     : (mat == 3) ? w3 : (mat == 4) ? w4 : w5;
      int row = t * 16 + (lane & 15);          // output column c
      int k0 = kk * 32 + (lane >> 4) * 8;
      unsigned int v[8];
      #pragma unroll
      for (int j = 0; j < 8; ++j) v[j] = f2bf(w[(k0 + j) * DIM + row]);
      uint4 o;
      o.x = v[0] | (v[1] << 16);
      o.y = v[2] | (v[3] << 16);
      o.z = v[4] | (v[5] << 16);
      o.w = v[6] | (v[7] << 16);
      ((uint4*)wfrag)[idx] = o;
    } else if (b < 80) {
      int i = (b - 48) * 256 + tid;
      if (i < N_GRAPHS * DIM) out[i] = 0.f;
    } else {
      int g = tid;  // 0..63
      if (g >= N_GRAPHS) return;
      int lo = 0, hi = N_NODES;
      while (lo < hi) { int m = (lo + hi) >> 1; if (batch[m] < g) lo = m + 1; else hi = m; }
      int s = lo;
      lo = 0; hi = N_NODES;
      int g1 = g + 1;
      while (lo < hi) { int m = (lo + hi) >> 1; if (batch[m] < g1) lo = m + 1; else hi = m; }
      int c = lo - s;
      inv_gcnt[g] = 1.0f / (float)(c > 1 ? c : 1);
    }
  }
}

// ---------------- CSR build (bucketed counting sort, no global atomics) ----

__global__ void k_escan(int* __restrict__ cnt, int* __restrict__ bb) {
  __shared__ int s[256];
  int t = threadIdx.x;
  int tot = 0;
  if (t < NB)
    for (int g = 0; g < GPART; ++g) tot += cnt[g * NB + t];
  s[t] = (t < NB) ? tot : 0;
  __syncthreads();
  for (int off = 1; off < 256; off <<= 1) {
    int v = (t >= off) ? s[t - off] : 0;
    __syncthreads();
    s[t] += v;
    __syncthreads();
  }
  if (t < NB) {
    int excl = s[t] - tot;
    bb[t] = excl;
    if (t == NB - 1) bb[NB] = s[t];  // == N_EDGES
    int run = excl;
    for (int g = 0; g < GPART; ++g) {
      int c = cnt[g * NB + t];
      cnt[g * NB + t] = run;
      run += c;
    }
  }
}

__global__ __launch_bounds__(256) void k_bucket(const int* __restrict__ ei,
                                                const int* __restrict__ cnt,
                                                unsigned int* __restrict__ bucketed) {
  __shared__ int lofs[NB];
  int t = threadIdx.x, g = blockIdx.x;
  if (t < NB) lofs[t] = cnt[g * NB + t];
  __syncthreads();
  int e0 = g * EPB;
  for (int i = t; i < EPB; i += 256) {
    int src = ei[e0 + i];
    int dst = ei[N_EDGES + e0 + i];
    int p = atomicAdd(&lofs[dst >> 8], 1);
    bucketed[p] = (unsigned int)src | ((unsigned int)(dst & 255) << 16);
  }
}

__global__ __launch_bounds__(256) void k_finalize(const unsigned int* __restrict__ bucketed,
                                                  const int* __restrict__ bb,
                                                  int* __restrict__ rowptr,
                                                  int* __restrict__ col) {
  __shared__ int h[256], s[256], c[256];
  int t = threadIdx.x, b = blockIdx.x;
  int s0 = bb[b], s1 = bb[b + 1];
  int n = s1 - s0;
  h[t] = 0;
  __syncthreads();
  for (int i = t; i < n; i += 256) atomicAdd(&h[bucketed[s0 + i] >> 16], 1);
  __syncthreads();
  s[t] = h[t];
  __syncthreads();
  for (int off = 1; off < 256; off <<= 1) {
    int v = (t >= off) ? s[t - off] : 0;
    __syncthreads();
    s[t] += v;
    __syncthreads();
  }
  int excl = s[t] - h[t];
  int node = b * 256 + t;
  if (node < N_NODES) rowptr[node] = s0 + excl;
  if (b == NB - 1 && t == 255) rowptr[N_NODES] = N_EDGES;
  c[t] = s0 + excl;
  __syncthreads();
  for (int i = t; i < n; i += 256) {
    unsigned int v = bucketed[s0 + i];
    int p = atomicAdd(&c[v >> 16], 1);
    col[p] = (int)(v & 0xffffu);
  }
}

// ---------------- per-layer kernels ----------------

#define ACC8(V)                                   \
  a0 += bf2f((unsigned short)((V).x & 0xffff));   \
  a1 += bf2f((unsigned short)((V).x >> 16));      \
  a2 += bf2f((unsigned short)((V).y & 0xffff));   \
  a3 += bf2f((unsigned short)((V).y >> 16));      \
  a4 += bf2f((unsigned short)((V).z & 0xffff));   \
  a5 += bf2f((unsigned short)((V).z >> 16));      \
  a6 += bf2f((unsigned short)((V).w & 0xffff));   \
  a7 += bf2f((unsigned short)((V).w >> 16));

// one wave per node; 4x16 lane groups, 3-deep rolling prefetch (12 loads in
// flight per wave). Per-group accumulation order unchanged: g, g+4, g+8...
__global__ __launch_bounds__(256) void k_agg(const unsigned short* __restrict__ xin,
                                             const int* __restrict__ rowptr,
                                             const int* __restrict__ col,
                                             unsigned short* __restrict__ meanbf) {
  int wid = (blockIdx.x * blockDim.x + threadIdx.x) >> 6;
  int lane = threadIdx.x & 63;
  if (wid >= N_NODES) return;
  int start = rowptr[wid], end = rowptr[wid + 1];
  int g = lane >> 4;    // neighbor slot 0..3
  int li = lane & 15;   // 16B chunk index within row

  float a0 = 0.f, a1 = 0.f, a2 = 0.f, a3 = 0.f;
  float a4 = 0.f, a5 = 0.f, a6 = 0.f, a7 = 0.f;
  for (int j0 = start; j0 < end; j0 += 64) {
    int m = end - j0;
    if (m > 64) m = 64;
    int idx = (lane < m) ? col[j0 + lane] : 0;
    int jj = g;
    if (jj < m) {
      int nb = __shfl(idx, jj);
      uint4 v = *(const uint4*)(xin + (size_t)nb * DIM + li * 8);
      jj += 4;
      if (jj < m) {
        int nb2 = __shfl(idx, jj);
        uint4 w = *(const uint4*)(xin + (size_t)nb2 * DIM + li * 8);
        jj += 4;
        if (jj < m) {
          int nb3 = __shfl(idx, jj);
          uint4 u = *(const uint4*)(xin + (size_t)nb3 * DIM + li * 8);
          for (jj += 4; jj < m; jj += 4) {
            int nb4 = __shfl(idx, jj);
            uint4 z = *(const uint4*)(xin + (size_t)nb4 * DIM + li * 8);
            ACC8(v);
            v = w; w = u; u = z;
          }
          ACC8(v);
          v = w; w = u;
        }
        ACC8(v);
        v = w;
      }
      ACC8(v);
    }
  }
  // reduce the 4 groups (lanes sharing li)
  a0 += __shfl_xor(a0, 16); a0 += __shfl_xor(a0, 32);
  a1 += __shfl_xor(a1, 16); a1 += __shfl_xor(a1, 32);
  a2 += __shfl_xor(a2, 16); a2 += __shfl_xor(a2, 32);
  a3 += __shfl_xor(a3, 16); a3 += __shfl_xor(a3, 32);
  a4 += __shfl_xor(a4, 16); a4 += __shfl_xor(a4, 32);
  a5 += __shfl_xor(a5, 16); a5 += __shfl_xor(a5, 32);
  a6 += __shfl_xor(a6, 16); a6 += __shfl_xor(a6, 32);
  a7 += __shfl_xor(a7, 16); a7 += __shfl_xor(a7, 32);

  if (g == 0) {
    int d = end - start;
    float sc = 1.0f / (float)(d > 1 ? d : 1);
    uint4 o;
    o.x = (unsigned int)f2bf(a0 * sc) | ((unsigned int)f2bf(a1 * sc) << 16);
    o.y = (unsigned int)f2bf(a2 * sc) | ((unsigned int)f2bf(a3 * sc) << 16);
    o.z = (unsigned int)f2bf(a4 * sc) | ((unsigned int)f2bf(a5 * sc) << 16);
    o.w = (unsigned int)f2bf(a6 * sc) | ((unsigned int)f2bf(a7 * sc) << 16);
    *(uint4*)(meanbf + (size_t)wid * DIM + li * 8) = o;
  }
}

// fused: h = [relu](mean @ Wl + xin @ Wr + b), row l2-normalize.
// 8 waves/block (512 thr). If pool_out != nullptr (layer 3): skip h store,
// accumulate graph-mean-pool directly (f32, pre-scaled by 1/count).
__global__ __launch_bounds__(512) void k_gemm(const unsigned short* __restrict__ meanbf,
                                              const unsigned short* __restrict__ xin,
                                              const unsigned short* __restrict__ wfragL,
                                              const unsigned short* __restrict__ wfragR,
                                              const float* __restrict__ bias,
                                              unsigned short* __restrict__ outbf,
                                              int relu,
                                              const int* __restrict__ batch,
                                              const float* __restrict__ inv_gcnt,
                                              float* __restrict__ pool_out) {
  __shared__ __align__(16) unsigned short wl[8 * 4 * 64 * 8];  // 32 KB
  __shared__ __align__(16) unsigned short wr[8 * 4 * 64 * 8];  // 32 KB
  const int tid = threadIdx.x;
  int wave = tid >> 6;
  int lane = tid & 63;
  int tb = blockIdx.x * 8 + wave;
  int lg = lane >> 4;   // 0..3
  int li = lane & 15;   // 0..15

  // A fragments first (global loads issue early, overlap LDS staging below)
  short8 am[4], ax[4];
  {
    int tbc = (tb < NTILES) ? tb : (NTILES - 1);
    const unsigned short* mrow = meanbf + ((size_t)(tbc * 16 + li)) * DIM + lg * 8;
    const unsigned short* xrow = xin + ((size_t)(tbc * 16 + li)) * DIM + lg * 8;
    #pragma unroll
    for (int kk = 0; kk < 4; ++kk) {
      am[kk] = *(const short8*)(mrow + kk * 32);
      ax[kk] = *(const short8*)(xrow + kk * 32);
    }
  }

  {
    const uint4* gl = (const uint4*)wfragL;
    const uint4* gr = (const uint4*)wfragR;
    uint4* sl = (uint4*)wl;
    uint4* sr = (uint4*)wr;
    #pragma unroll
    for (int i = 0; i < 4; ++i) {  // 2048 uint4 per array / 512 threads
      sl[tid + 512 * i] = gl[tid + 512 * i];
      sr[tid + 512 * i] = gr[tid + 512 * i];
    }
  }
  __syncthreads();
  if (tb >= NTILES) return;

  f32x4 acc[8];
  #pragma unroll
  for (int t = 0; t < 8; ++t) {
    f32x4 c = {0.f, 0.f, 0.f, 0.f};
    #pragma unroll
    for (int kk = 0; kk < 4; ++kk) {
      short8 bl = *(const short8*)(wl + (((t * 4 + kk) * 64 + lane) * 8));
      c = __builtin_amdgcn_mfma_f32_16x16x32_bf16(am[kk], bl, c, 0, 0, 0);
      short8 br = *(const short8*)(wr + (((t * 4 + kk) * 64 + lane) * 8));
      c = __builtin_amdgcn_mfma_f32_16x16x32_bf16(ax[kk], br, c, 0, 0, 0);
    }
    float bv = bias[t * 16 + li];
    #pragma unroll
    for (int r = 0; r < 4; ++r) {
      float v = c[r] + bv;
      if (relu) v = fmaxf(v, 0.f);
      c[r] = v;
    }
    acc[t] = c;
  }

  // l2 norm per output row: row = tb*16 + lg*4 + r; cols spread over t and li.
  float scale[4];
  #pragma unroll
  for (int r = 0; r < 4; ++r) {
    float s = 0.f;
    #pragma unroll
    for (int t = 0; t < 8; ++t) s += acc[t][r] * acc[t][r];
    s += __shfl_xor(s, 1);
    s += __shfl_xor(s, 2);
    s += __shfl_xor(s, 4);
    s += __shfl_xor(s, 8);
    float n = sqrtf(s);
    scale[r] = 1.0f / fmaxf(n, 1e-12f);
  }

  if (pool_out) {
    // fused global-mean-pool; batch sorted -> few graphs per tile.
    int rowbase = tb * 16 + lg * 4;
    int bg[4];
    #pragma unroll
    for (int r = 0; r < 4; ++r) bg[r] = batch[rowbase + r];
    int g_cur = batch[tb * 16];  // wave-uniform
    while (true) {
      float p[8];
      #pragma unroll
      for (int t = 0; t < 8; ++t) {
        float s = 0.f;
        #pragma unroll
        for (int r = 0; r < 4; ++r)
          if (bg[r] == g_cur) s += acc[t][r] * scale[r];
        p[t] = s;
      }
      #pragma unroll
      for (int t = 0; t < 8; ++t) {
        p[t] += __shfl_xor(p[t], 16);
        p[t] += __shfl_xor(p[t], 32);
      }
      if (lg == 0) {
        float inv = inv_gcnt[g_cur];
        #pragma unroll
        for (int t = 0; t < 8; ++t)
          atomicAdd(&pool_out[g_cur * DIM + t * 16 + li], p[t] * inv);
      }
      // next graph id within this 16-row tile (bg uniform across li lanes)
      int nxt = 0x7fffffff;
      #pragma unroll
      for (int r = 0; r < 4; ++r)
        if (bg[r] > g_cur && bg[r] < nxt) nxt = bg[r];
      nxt = min(nxt, __shfl_xor(nxt, 16));
      nxt = min(nxt, __shfl_xor(nxt, 32));
      if (nxt == 0x7fffffff) break;
      g_cur = nxt;
    }
  } else {
    #pragma unroll
    for (int t = 0; t < 8; ++t) {
      #pragma unroll
      for (int r = 0; r < 4; ++r) {
        outbf[((size_t)(tb * 16 + lg * 4 + r)) * DIM + t * 16 + li] =
            f2bf(acc[t][r] * scale[r]);
      }
    }
  }
}

// ---------------- launch ----------------

extern "C" void kernel_launch(void* const* d_in, const int* in_sizes, int n_in,
                              void* d_out, int out_size, void* d_ws, size_t ws_size,
                              hipStream_t stream) {
  const float* x   = (const float*)d_in[0];
  const int* ei    = (const int*)d_in[1];
  const int* batch = (const int*)d_in[2];
  const float* Wl1 = (const float*)d_in[3];
  const float* Wr1 = (const float*)d_in[4];
  const float* b1  = (const float*)d_in[5];
  const float* Wl2 = (const float*)d_in[6];
  const float* Wr2 = (const float*)d_in[7];
  const float* b2  = (const float*)d_in[8];
  const float* Wl3 = (const float*)d_in[9];
  const float* Wr3 = (const float*)d_in[10];
  const float* b3  = (const float*)d_in[11];
  float* out = (float*)d_out;

  char* ws = (char*)d_ws;
  size_t off = 0;
  auto alloc = [&](size_t bytes) {
    void* p = ws + off;
    off += (bytes + 255) & ~(size_t)255;
    return p;
  };
  unsigned short* xbf   = (unsigned short*)alloc((size_t)N_NODES * DIM * 2);
  unsigned short* hB    = (unsigned short*)alloc((size_t)N_NODES * DIM * 2);
  unsigned short* hC    = (unsigned short*)alloc((size_t)N_NODES * DIM * 2);
  unsigned short* mean  = (unsigned short*)alloc((size_t)N_NODES * DIM * 2);
  unsigned short* wfrag = (unsigned short*)alloc((size_t)6 * 2048 * 16);
  int* rowptr = (int*)alloc((size_t)(N_NODES + 1) * 4);
  int* col    = (int*)alloc((size_t)N_EDGES * 4);
  int* cnt    = (int*)alloc((size_t)GPART * NB * 4);
  int* bb     = (int*)alloc((size_t)(NB + 1) * 4);
  unsigned int* bucketed = (unsigned int*)alloc((size_t)N_EDGES * 4);
  float* inv_gcnt = (float*)alloc((size_t)N_GRAPHS * 4);

  // front: hist + xbf + (wfrag, zero out, inv_gcnt)
  k_front<<<GPART + XBF_BLKS + 81, 256, 0, stream>>>(
      ei, cnt, x, xbf, Wl1, Wr1, Wl2, Wr2, Wl3, Wr3, wfrag, out, batch, inv_gcnt);

  // CSR build
  k_escan<<<1, 256, 0, stream>>>(cnt, bb);
  k_bucket<<<GPART, 256, 0, stream>>>(ei, cnt, bucketed);
  k_finalize<<<NB, 256, 0, stream>>>(bucketed, bb, rowptr, col);

  // layer 1
  k_agg<<<12500, 256, 0, stream>>>(xbf, rowptr, col, mean);
  k_gemm<<<391, 512, 0, stream>>>(mean, xbf, wfrag + 0 * 16384, wfrag + 1 * 16384,
                                  b1, hB, 1, batch, inv_gcnt, nullptr);
  // layer 2
  k_agg<<<12500, 256, 0, stream>>>(hB, rowptr, col, mean);
  k_gemm<<<391, 512, 0, stream>>>(mean, hB, wfrag + 2 * 16384, wfrag + 3 * 16384,
                                  b2, hC, 1, batch, inv_gcnt, nullptr);
  // layer 3 (fused mean-pool with pre-scaled 1/count, no h store, no k_div)
  k_agg<<<12500, 256, 0, stream>>>(hC, rowptr, col, mean);
  k_gemm<<<391, 512, 0, stream>>>(mean, hC, wfrag + 4 * 16384, wfrag + 5 * 16384,
                                  b3, nullptr, 0, batch, inv_gcnt, out);
}